// Round 1
// baseline (1061.725 us; speedup 1.0000x reference)
//
#include <hip/hip_runtime.h>

#define N_NODES 200000
#define C 256
#define VC 16
#define VD 3
#define M_MOTIFS 50000

// ---------------------------------------------------------------------------
// Pass 1: scatter-add s rows, v rows, and counts into ws accumulators.
// One wave (64 lanes) per node: lane i handles s[node, 4i:4i+4] via float4.
// ---------------------------------------------------------------------------
__global__ __launch_bounds__(256) void scatter_kernel(
    const float* __restrict__ s, const float* __restrict__ v,
    const int* __restrict__ seg,
    float* __restrict__ s_acc, float* __restrict__ v_acc,
    float* __restrict__ cnt, int n) {
  int gid  = blockIdx.x * blockDim.x + threadIdx.x;
  int node = gid >> 6;
  int lane = threadIdx.x & 63;
  if (node >= n) return;
  int m = seg[node];

  float4 sv = ((const float4*)(s + (size_t)node * C))[lane];
  float* dst = s_acc + (size_t)m * C + lane * 4;
  atomicAdd(dst + 0, sv.x);
  atomicAdd(dst + 1, sv.y);
  atomicAdd(dst + 2, sv.z);
  atomicAdd(dst + 3, sv.w);

  if (lane < VC * VD) {
    atomicAdd(v_acc + (size_t)m * (VC * VD) + lane,
              v[(size_t)node * (VC * VD) + lane]);
  }
  if (lane == 0) atomicAdd(cnt + m, 1.0f);
}

// ---------------------------------------------------------------------------
// Pass 2: s_out[m,o] = (s_acc[m,:]/max(cnt,1)) . Ws[o,:] + bs[o]
// 64x64 tile, BK=16, 4x4 acc per thread. fp32 vector GEMM (no fp32 MFMA).
// ---------------------------------------------------------------------------
#define BM 64
#define BN 64
#define BK 16

__global__ __launch_bounds__(256) void gemm_s_kernel(
    const float* __restrict__ s_acc, const float* __restrict__ cnt,
    const float* __restrict__ Ws, const float* __restrict__ bs,
    float* __restrict__ out) {
  // +4 pad: row = 272 B, keeps float4 LDS reads 16B-aligned, breaks 32-stride
  __shared__ float As[BK][BM + 4];
  __shared__ float Bs[BK][BN + 4];
  int tid = threadIdx.x;
  int m0 = blockIdx.x * BM;
  int n0 = blockIdx.y * BN;
  int tm = tid >> 4;   // 0..15  (row group)
  int tn = tid & 15;   // 0..15  (col group; consecutive lanes -> coalesced store)
  float acc[4][4] = {};

  int lrow = tid >> 2;        // 0..63 staging row
  int lk4  = (tid & 3) * 4;   // 0,4,8,12 staging k offset

  for (int k0 = 0; k0 < C; k0 += BK) {
    int gm = m0 + lrow;
    float4 a = make_float4(0.f, 0.f, 0.f, 0.f);
    if (gm < M_MOTIFS)
      a = *(const float4*)(s_acc + (size_t)gm * C + k0 + lk4);
    As[lk4 + 0][lrow] = a.x;
    As[lk4 + 1][lrow] = a.y;
    As[lk4 + 2][lrow] = a.z;
    As[lk4 + 3][lrow] = a.w;

    int gn = n0 + lrow;  // always < 256
    float4 b = *(const float4*)(Ws + (size_t)gn * C + k0 + lk4);
    Bs[lk4 + 0][lrow] = b.x;
    Bs[lk4 + 1][lrow] = b.y;
    Bs[lk4 + 2][lrow] = b.z;
    Bs[lk4 + 3][lrow] = b.w;
    __syncthreads();

#pragma unroll
    for (int kk = 0; kk < BK; ++kk) {
      float4 a4 = *(const float4*)&As[kk][tm * 4];
      float4 b4 = *(const float4*)&Bs[kk][tn * 4];
      float av[4] = {a4.x, a4.y, a4.z, a4.w};
      float bw[4] = {b4.x, b4.y, b4.z, b4.w};
#pragma unroll
      for (int i = 0; i < 4; ++i)
#pragma unroll
        for (int j = 0; j < 4; ++j)
          acc[i][j] += av[i] * bw[j];
    }
    __syncthreads();
  }

#pragma unroll
  for (int i = 0; i < 4; ++i) {
    int gm = m0 + tm * 4 + i;
    if (gm >= M_MOTIFS) continue;
    float rc = 1.0f / fmaxf(cnt[gm], 1.0f);
    int gn = n0 + tn * 4;
    float4 o;
    o.x = acc[i][0] * rc + bs[gn + 0];
    o.y = acc[i][1] * rc + bs[gn + 1];
    o.z = acc[i][2] * rc + bs[gn + 2];
    o.w = acc[i][3] * rc + bs[gn + 3];
    *(float4*)(out + (size_t)gm * C + gn) = o;
  }
}

// ---------------------------------------------------------------------------
// Pass 3: v_out[m,o,d] = sum_c Wv[o,c] * (v_acc[m,c,d]/max(cnt,1)) + bv[o]
// One thread per output element; Wv/bv staged in LDS.
// ---------------------------------------------------------------------------
__global__ __launch_bounds__(256) void pool_v_kernel(
    const float* __restrict__ v_acc, const float* __restrict__ cnt,
    const float* __restrict__ Wv, const float* __restrict__ bv,
    float* __restrict__ v_out) {
  __shared__ float w[VC * VC];
  __shared__ float b[VC];
  if (threadIdx.x < VC * VC) w[threadIdx.x] = Wv[threadIdx.x];
  if (threadIdx.x < VC) b[threadIdx.x] = bv[threadIdx.x];
  __syncthreads();

  int idx = blockIdx.x * blockDim.x + threadIdx.x;
  const int total = M_MOTIFS * VC * VD;
  if (idx >= total) return;
  int m = idx / (VC * VD);
  int r = idx - m * (VC * VD);
  int o = r / VD;
  int d = r - o * VD;

  float rc = 1.0f / fmaxf(cnt[m], 1.0f);
  const float* vrow = v_acc + (size_t)m * (VC * VD) + d;
  const float* wrow = w + o * VC;
  float acc = 0.f;
#pragma unroll
  for (int c = 0; c < VC; ++c) acc += wrow[c] * vrow[c * VD];
  v_out[idx] = acc * rc + b[o];
}

extern "C" void kernel_launch(void* const* d_in, const int* in_sizes, int n_in,
                              void* d_out, int out_size, void* d_ws, size_t ws_size,
                              hipStream_t stream) {
  const float* s  = (const float*)d_in[0];
  const float* v  = (const float*)d_in[1];
  const int*   seg = (const int*)d_in[2];
  const float* Ws = (const float*)d_in[3];
  const float* bs = (const float*)d_in[4];
  const float* Wv = (const float*)d_in[5];
  const float* bv = (const float*)d_in[6];

  float* out   = (float*)d_out;
  float* s_out = out;
  float* v_out = out + (size_t)M_MOTIFS * C;

  float* s_acc = (float*)d_ws;
  float* v_acc = s_acc + (size_t)M_MOTIFS * C;
  float* cnt   = v_acc + (size_t)M_MOTIFS * (VC * VD);
  size_t ws_bytes = (size_t)M_MOTIFS * (C + VC * VD + 1) * sizeof(float);

  hipMemsetAsync(d_ws, 0, ws_bytes, stream);

  {
    int threads = N_NODES * 64;  // one wave per node
    scatter_kernel<<<(threads + 255) / 256, 256, 0, stream>>>(
        s, v, seg, s_acc, v_acc, cnt, N_NODES);
  }
  {
    dim3 grid((M_MOTIFS + BM - 1) / BM, C / BN);
    gemm_s_kernel<<<grid, 256, 0, stream>>>(s_acc, cnt, Ws, bs, s_out);
  }
  {
    int total = M_MOTIFS * VC * VD;
    pool_v_kernel<<<(total + 255) / 256, 256, 0, stream>>>(
        v_acc, cnt, Wv, bv, v_out);
  }
}

// Round 3
// 402.586 us; speedup vs baseline: 2.6373x; 2.6373x over previous
//
#include <hip/hip_runtime.h>

#define N_NODES 200000
#define C 256
#define VC 16
#define VD 3
#define VDIM (VC * VD)   // 48
#define M_MOTIFS 50000

#define SCAN_B 256
#define NB ((M_MOTIFS + SCAN_B - 1) / SCAN_B)   // 196

typedef __attribute__((ext_vector_type(8))) __bf16 bf16x8;
typedef __attribute__((ext_vector_type(4))) float f32x4;

__device__ __forceinline__ unsigned short f2bf(float x) {
  unsigned u = __builtin_bit_cast(unsigned, x);
  u += 0x7fffu + ((u >> 16) & 1u);   // RNE
  return (unsigned short)(u >> 16);
}

// ---------------------------------------------------------------------------
// K1: count nodes per motif (int atomics only)
// ---------------------------------------------------------------------------
__global__ __launch_bounds__(256) void count_kernel(
    const int* __restrict__ seg, int* __restrict__ cnt, int n) {
  int i = blockIdx.x * blockDim.x + threadIdx.x;
  if (i < n) atomicAdd(&cnt[seg[i]], 1);
}

// K2a: per-block sums of cnt
__global__ __launch_bounds__(SCAN_B) void scan_blocksum_kernel(
    const int* __restrict__ cnt, int* __restrict__ blocksums) {
  __shared__ int sm[SCAN_B];
  int t = threadIdx.x;
  int i = blockIdx.x * SCAN_B + t;
  sm[t] = (i < M_MOTIFS) ? cnt[i] : 0;
  __syncthreads();
  for (int off = SCAN_B / 2; off > 0; off >>= 1) {
    if (t < off) sm[t] += sm[t + off];
    __syncthreads();
  }
  if (t == 0) blocksums[blockIdx.x] = sm[0];
}

// K2b: exclusive scan of blocksums (single block)
__global__ __launch_bounds__(SCAN_B) void scan_top_kernel(
    int* __restrict__ blocksums) {
  __shared__ int sm[SCAN_B];
  int t = threadIdx.x;
  sm[t] = (t < NB) ? blocksums[t] : 0;
  __syncthreads();
  for (int off = 1; off < SCAN_B; off <<= 1) {
    int y = (t >= off) ? sm[t - off] : 0;
    __syncthreads();
    sm[t] += y;
    __syncthreads();
  }
  if (t < NB) blocksums[t] = (t == 0) ? 0 : sm[t - 1];
}

// K2c: per-block exclusive scan + base -> offs (segment starts)
__global__ __launch_bounds__(SCAN_B) void scan_final_kernel(
    const int* __restrict__ cnt, const int* __restrict__ blocksums,
    int* __restrict__ offs) {
  __shared__ int sm[SCAN_B];
  int t = threadIdx.x;
  int i = blockIdx.x * SCAN_B + t;
  int x = (i < M_MOTIFS) ? cnt[i] : 0;
  sm[t] = x;
  __syncthreads();
  for (int off = 1; off < SCAN_B; off <<= 1) {
    int y = (t >= off) ? sm[t - off] : 0;
    __syncthreads();
    sm[t] += y;
    __syncthreads();
  }
  if (i < M_MOTIFS) offs[i] = blocksums[blockIdx.x] + sm[t] - x;
}

// K3: place node ids (offs[m] becomes segment END afterwards)
__global__ __launch_bounds__(256) void place_kernel(
    const int* __restrict__ seg, int* __restrict__ offs,
    int* __restrict__ nodelist, int n) {
  int i = blockIdx.x * blockDim.x + threadIdx.x;
  if (i >= n) return;
  int m = seg[i];
  int pos = atomicAdd(&offs[m], 1);
  nodelist[pos] = i;
}

// K4: Ws fp32 -> bf16 (one-shot, 64K elems)
__global__ __launch_bounds__(256) void cvt_ws_kernel(
    const float* __restrict__ W, unsigned short* __restrict__ Wb) {
  int i = blockIdx.x * blockDim.x + threadIdx.x;
  if (i < C * C) Wb[i] = f2bf(W[i]);
}

// ---------------------------------------------------------------------------
// K5: gather + mean. One wave per motif. Writes s_motif (bf16) and fuses the
//     v 16x16 linear via shuffles -> v_out directly (no v_motif staging).
// ---------------------------------------------------------------------------
__global__ __launch_bounds__(256) void gather_kernel(
    const float* __restrict__ s, const float* __restrict__ v,
    const int* __restrict__ offs, const int* __restrict__ nodelist,
    const float* __restrict__ Wv, const float* __restrict__ bv,
    unsigned short* __restrict__ s_motif, float* __restrict__ v_out) {
  int wave = (blockIdx.x * blockDim.x + threadIdx.x) >> 6;
  int lane = threadIdx.x & 63;
  if (wave >= M_MOTIFS) return;
  int m = wave;
  int end = offs[m];
  int start = (m == 0) ? 0 : offs[m - 1];

  float4 acc = make_float4(0.f, 0.f, 0.f, 0.f);
  float vacc = 0.f;
  for (int j = start; j < end; ++j) {
    int idx = nodelist[j];
    float4 sv = ((const float4*)(s + (size_t)idx * C))[lane];
    acc.x += sv.x; acc.y += sv.y; acc.z += sv.z; acc.w += sv.w;
    if (lane < VDIM) vacc += v[(size_t)idx * VDIM + lane];
  }
  int k = end - start;
  float rc = 1.0f / (float)max(k, 1);

  ushort4 o;
  o.x = f2bf(acc.x * rc); o.y = f2bf(acc.y * rc);
  o.z = f2bf(acc.z * rc); o.w = f2bf(acc.w * rc);
  ((ushort4*)(s_motif + (size_t)m * C))[lane] = o;

  float vm = vacc * rc;   // lane c*3+d holds vmean[c][d]
  if (lane < VDIM) {
    int oo = lane / 3, d = lane - oo * 3;
    float vo = bv[oo];
#pragma unroll
    for (int c = 0; c < VC; ++c)
      vo += Wv[oo * VC + c] * __shfl(vm, c * 3 + d, 64);
    v_out[(size_t)m * VDIM + lane] = vo;
  }
}

// ---------------------------------------------------------------------------
// K6: bf16 MFMA GEMM: out[m][n] = sum_k A[m][k]*Ws[n][k] + bs[n]
//     128x128 tile, BK=32, 4 waves (2x2), each wave 4x4 of 16x16x32 MFMAs.
//     A-op layout A[m=lane&15][k=(lane>>4)*8+j]; C/D col=lane&15,
//     row=(lane>>4)*4+reg  [m89/m91].
// ---------------------------------------------------------------------------
__global__ __launch_bounds__(256) void gemm_mfma_kernel(
    const unsigned short* __restrict__ A16,   // s_motif bf16 [M][256]
    const unsigned short* __restrict__ B16,   // Ws bf16 [256][256]
    const float* __restrict__ bs, float* __restrict__ out) {
  __shared__ unsigned short As[128 * 32];
  __shared__ unsigned short Bs[128 * 32];
  int tid = threadIdx.x;
  int wave = tid >> 6, lane = tid & 63;
  int m0 = blockIdx.x * 128;
  int n0 = blockIdx.y * 128;
  int wm = (wave >> 1) * 64, wn = (wave & 1) * 64;

  f32x4 acc[4][4] = {};

  int t4 = tid >> 2;            // 0..63 staging row
  int kc = (tid & 3) * 8;       // staging k elem offset (16B chunks)
  int rl = lane & 15;
  int kq = (lane >> 4) * 8;

  for (int k0 = 0; k0 < C; k0 += 32) {
    // stage A/B tiles (rows m0..m0+127 / n0..n0+127, k0..k0+31), 16B per store
    *(uint4*)&As[(size_t)t4 * 32 + kc] =
        *(const uint4*)&A16[(size_t)(m0 + t4) * C + k0 + kc];
    *(uint4*)&As[(size_t)(64 + t4) * 32 + kc] =
        *(const uint4*)&A16[(size_t)(m0 + 64 + t4) * C + k0 + kc];
    *(uint4*)&Bs[(size_t)t4 * 32 + kc] =
        *(const uint4*)&B16[(size_t)(n0 + t4) * C + k0 + kc];
    *(uint4*)&Bs[(size_t)(64 + t4) * 32 + kc] =
        *(const uint4*)&B16[(size_t)(n0 + 64 + t4) * C + k0 + kc];
    __syncthreads();

    bf16x8 af[4], bfr[4];
#pragma unroll
    for (int i = 0; i < 4; ++i)
      af[i] = *(const bf16x8*)&As[(size_t)(wm + i * 16 + rl) * 32 + kq];
#pragma unroll
    for (int j = 0; j < 4; ++j)
      bfr[j] = *(const bf16x8*)&Bs[(size_t)(wn + j * 16 + rl) * 32 + kq];
#pragma unroll
    for (int i = 0; i < 4; ++i)
#pragma unroll
      for (int j = 0; j < 4; ++j)
        acc[i][j] = __builtin_amdgcn_mfma_f32_16x16x32_bf16(
            af[i], bfr[j], acc[i][j], 0, 0, 0);
    __syncthreads();
  }

  int rq = (lane >> 4) * 4;
#pragma unroll
  for (int j = 0; j < 4; ++j) {
    int cn = n0 + wn + j * 16 + rl;
    float bias = bs[cn];
#pragma unroll
    for (int i = 0; i < 4; ++i) {
#pragma unroll
      for (int r = 0; r < 4; ++r) {
        int gm = m0 + wm + i * 16 + rq + r;
        if (gm < M_MOTIFS) out[(size_t)gm * C + cn] = acc[i][j][r] + bias;
      }
    }
  }
}

extern "C" void kernel_launch(void* const* d_in, const int* in_sizes, int n_in,
                              void* d_out, int out_size, void* d_ws, size_t ws_size,
                              hipStream_t stream) {
  const float* s  = (const float*)d_in[0];
  const float* v  = (const float*)d_in[1];
  const int*   seg = (const int*)d_in[2];
  const float* Ws = (const float*)d_in[3];
  const float* bs = (const float*)d_in[4];
  const float* Wv = (const float*)d_in[5];
  const float* bv = (const float*)d_in[6];

  float* out   = (float*)d_out;
  float* s_out = out;
  float* v_out = out + (size_t)M_MOTIFS * C;

  // ws layout (26.93 MB total — was 62 MB in R2; suspected ws overflow):
  // [cnt M][offs M][nodelist N][blocksums 256][Ws_bf16 64K][s_motif M*C bf16]
  int* cnt       = (int*)d_ws;
  int* offs      = cnt + M_MOTIFS;
  int* nodelist  = offs + M_MOTIFS;
  int* blocksums = nodelist + N_NODES;
  unsigned short* Wsb     = (unsigned short*)(blocksums + 256);
  unsigned short* s_motif = Wsb + (size_t)C * C;

  hipMemsetAsync(cnt, 0, M_MOTIFS * sizeof(int), stream);

  count_kernel<<<(N_NODES + 255) / 256, 256, 0, stream>>>(seg, cnt, N_NODES);
  scan_blocksum_kernel<<<NB, SCAN_B, 0, stream>>>(cnt, blocksums);
  scan_top_kernel<<<1, SCAN_B, 0, stream>>>(blocksums);
  scan_final_kernel<<<NB, SCAN_B, 0, stream>>>(cnt, blocksums, offs);
  place_kernel<<<(N_NODES + 255) / 256, 256, 0, stream>>>(seg, offs, nodelist,
                                                          N_NODES);
  cvt_ws_kernel<<<(C * C + 255) / 256, 256, 0, stream>>>(Ws, Wsb);
  {
    int threads = M_MOTIFS * 64;  // one wave per motif
    gather_kernel<<<(threads + 255) / 256, 256, 0, stream>>>(
        s, v, offs, nodelist, Wv, bv, s_motif, v_out);
  }
  {
    dim3 grid((M_MOTIFS + 127) / 128, C / 128);
    gemm_mfma_kernel<<<grid, 256, 0, stream>>>(s_motif, Wsb, bs, s_out);
  }
}

// Round 4
// 397.220 us; speedup vs baseline: 2.6729x; 1.0135x over previous
//
#include <hip/hip_runtime.h>

#define N_NODES 200000
#define C 256
#define VC 16
#define VD 3
#define VDIM (VC * VD)   // 48
#define M_MOTIFS 50000

#define SCAN_B 256
#define NB ((M_MOTIFS + SCAN_B - 1) / SCAN_B)   // 196

typedef __attribute__((ext_vector_type(8))) __bf16 bf16x8;
typedef __attribute__((ext_vector_type(4))) float f32x4;

__device__ __forceinline__ unsigned short f2bf(float x) {
  unsigned u = __builtin_bit_cast(unsigned, x);
  u += 0x7fffu + ((u >> 16) & 1u);   // RNE
  return (unsigned short)(u >> 16);
}

// async global->LDS, 16B per lane; LDS dest = wave-uniform base + lane*16
__device__ __forceinline__ void async_copy16(const void* g, void* l) {
  __builtin_amdgcn_global_load_lds(
      (const __attribute__((address_space(1))) unsigned int*)g,
      (__attribute__((address_space(3))) unsigned int*)l, 16, 0, 0);
}

// ---------------------------------------------------------------------------
// K1: count nodes per motif (int atomics only)
// ---------------------------------------------------------------------------
__global__ __launch_bounds__(256) void count_kernel(
    const int* __restrict__ seg, int* __restrict__ cnt, int n) {
  int i = blockIdx.x * blockDim.x + threadIdx.x;
  if (i < n) atomicAdd(&cnt[seg[i]], 1);
}

// K2a: per-block sums of cnt
__global__ __launch_bounds__(SCAN_B) void scan_blocksum_kernel(
    const int* __restrict__ cnt, int* __restrict__ blocksums) {
  __shared__ int sm[SCAN_B];
  int t = threadIdx.x;
  int i = blockIdx.x * SCAN_B + t;
  sm[t] = (i < M_MOTIFS) ? cnt[i] : 0;
  __syncthreads();
  for (int off = SCAN_B / 2; off > 0; off >>= 1) {
    if (t < off) sm[t] += sm[t + off];
    __syncthreads();
  }
  if (t == 0) blocksums[blockIdx.x] = sm[0];
}

// K2b: exclusive scan of blocksums (single block)
__global__ __launch_bounds__(SCAN_B) void scan_top_kernel(
    int* __restrict__ blocksums) {
  __shared__ int sm[SCAN_B];
  int t = threadIdx.x;
  sm[t] = (t < NB) ? blocksums[t] : 0;
  __syncthreads();
  for (int off = 1; off < SCAN_B; off <<= 1) {
    int y = (t >= off) ? sm[t - off] : 0;
    __syncthreads();
    sm[t] += y;
    __syncthreads();
  }
  if (t < NB) blocksums[t] = (t == 0) ? 0 : sm[t - 1];
}

// K2c: per-block exclusive scan + base -> offs (segment starts)
__global__ __launch_bounds__(SCAN_B) void scan_final_kernel(
    const int* __restrict__ cnt, const int* __restrict__ blocksums,
    int* __restrict__ offs) {
  __shared__ int sm[SCAN_B];
  int t = threadIdx.x;
  int i = blockIdx.x * SCAN_B + t;
  int x = (i < M_MOTIFS) ? cnt[i] : 0;
  sm[t] = x;
  __syncthreads();
  for (int off = 1; off < SCAN_B; off <<= 1) {
    int y = (t >= off) ? sm[t - off] : 0;
    __syncthreads();
    sm[t] += y;
    __syncthreads();
  }
  if (i < M_MOTIFS) offs[i] = blocksums[blockIdx.x] + sm[t] - x;
}

// K3: place node ids (offs[m] becomes segment END afterwards)
__global__ __launch_bounds__(256) void place_kernel(
    const int* __restrict__ seg, int* __restrict__ offs,
    int* __restrict__ nodelist, int n) {
  int i = blockIdx.x * blockDim.x + threadIdx.x;
  if (i >= n) return;
  int m = seg[i];
  int pos = atomicAdd(&offs[m], 1);
  nodelist[pos] = i;
}

// K4: Ws fp32 -> bf16 (64K elems)
__global__ __launch_bounds__(256) void cvt_ws_kernel(
    const float* __restrict__ W, unsigned short* __restrict__ Wb) {
  int i = blockIdx.x * blockDim.x + threadIdx.x;
  if (i < C * C) Wb[i] = f2bf(W[i]);
}

// ---------------------------------------------------------------------------
// K5: gather + mean. One wave per motif. Node ids prefetched in ONE coalesced
//     load and broadcast via shfl; s-row loads 4-way unrolled (independent,
//     4+ in flight). Fuses the v 16x16 linear via shuffles -> v_out direct.
// ---------------------------------------------------------------------------
__global__ __launch_bounds__(256) void gather_kernel(
    const float* __restrict__ s, const float* __restrict__ v,
    const int* __restrict__ offs, const int* __restrict__ nodelist,
    const float* __restrict__ Wv, const float* __restrict__ bv,
    unsigned short* __restrict__ s_motif, float* __restrict__ v_out) {
  int wave = (blockIdx.x * blockDim.x + threadIdx.x) >> 6;
  int lane = threadIdx.x & 63;
  if (wave >= M_MOTIFS) return;
  int m = wave;
  int end = offs[m];
  int start = (m == 0) ? 0 : offs[m - 1];
  int k = end - start;

  // one coalesced load covers up to 64 node ids
  int nid = 0;
  if (start + lane < end) nid = nodelist[start + lane];

  float4 acc = make_float4(0.f, 0.f, 0.f, 0.f);
  float vacc = 0.f;
  int n64 = min(k, 64);
  int jj = 0;
  for (; jj + 4 <= n64; jj += 4) {
    int i0 = __shfl(nid, jj + 0, 64);
    int i1 = __shfl(nid, jj + 1, 64);
    int i2 = __shfl(nid, jj + 2, 64);
    int i3 = __shfl(nid, jj + 3, 64);
    float4 a = ((const float4*)(s + (size_t)i0 * C))[lane];
    float4 b = ((const float4*)(s + (size_t)i1 * C))[lane];
    float4 c = ((const float4*)(s + (size_t)i2 * C))[lane];
    float4 d = ((const float4*)(s + (size_t)i3 * C))[lane];
    acc.x += (a.x + b.x) + (c.x + d.x);
    acc.y += (a.y + b.y) + (c.y + d.y);
    acc.z += (a.z + b.z) + (c.z + d.z);
    acc.w += (a.w + b.w) + (c.w + d.w);
    if (lane < VDIM) {
      float va = v[(size_t)i0 * VDIM + lane];
      float vb = v[(size_t)i1 * VDIM + lane];
      float vc = v[(size_t)i2 * VDIM + lane];
      float vd = v[(size_t)i3 * VDIM + lane];
      vacc += (va + vb) + (vc + vd);
    }
  }
  for (; jj < n64; ++jj) {
    int i0 = __shfl(nid, jj, 64);
    float4 a = ((const float4*)(s + (size_t)i0 * C))[lane];
    acc.x += a.x; acc.y += a.y; acc.z += a.z; acc.w += a.w;
    if (lane < VDIM) vacc += v[(size_t)i0 * VDIM + lane];
  }
  // rare tail: segments with > 64 nodes
  for (int j = start + 64; j < end; ++j) {
    int i0 = nodelist[j];
    float4 a = ((const float4*)(s + (size_t)i0 * C))[lane];
    acc.x += a.x; acc.y += a.y; acc.z += a.z; acc.w += a.w;
    if (lane < VDIM) vacc += v[(size_t)i0 * VDIM + lane];
  }

  float rc = 1.0f / (float)max(k, 1);
  ushort4 o;
  o.x = f2bf(acc.x * rc); o.y = f2bf(acc.y * rc);
  o.z = f2bf(acc.z * rc); o.w = f2bf(acc.w * rc);
  ((ushort4*)(s_motif + (size_t)m * C))[lane] = o;

  float vm = vacc * rc;   // lane c*3+d holds vmean[c][d]
  if (lane < VDIM) {
    int oo = lane / 3, d = lane - oo * 3;
    float vo = bv[oo];
#pragma unroll
    for (int c = 0; c < VC; ++c)
      vo += Wv[oo * VC + c] * __shfl(vm, c * 3 + d, 64);
    v_out[(size_t)m * VDIM + lane] = vo;
  }
}

// ---------------------------------------------------------------------------
// K6: bf16 MFMA GEMM with global_load_lds width=16 staging (m97 structure).
//     128x128 tile, BK=32, 4 waves (2x2), each wave 4x4 of 16x16x32 MFMAs.
//     Staging: wave w stages rows [w*32, w*32+32) of A and B; one
//     global_load_lds covers 16 rows (64 lanes x 16B, row = 64B = 4 lanes).
// ---------------------------------------------------------------------------
__global__ __launch_bounds__(256) void gemm_mfma_kernel(
    const unsigned short* __restrict__ A16,   // s_motif bf16 [M][256]
    const unsigned short* __restrict__ B16,   // Ws bf16 [256][256]
    const float* __restrict__ bs, float* __restrict__ out) {
  __shared__ unsigned short As[128 * 32];
  __shared__ unsigned short Bs[128 * 32];
  int tid = threadIdx.x;
  int wave = tid >> 6, lane = tid & 63;
  int m0 = blockIdx.x * 128;
  int n0 = blockIdx.y * 128;
  int wm = (wave >> 1) * 64, wn = (wave & 1) * 64;

  f32x4 acc[4][4] = {};

  int srow = lane >> 2;        // 0..15: row within a 16-row staging group
  int kc   = (lane & 3) * 8;   // k element offset (16B chunk)
  int rl = lane & 15;
  int kq = (lane >> 4) * 8;

  const unsigned short* Ag = A16 + (size_t)(m0 + wave * 32) * C;
  const unsigned short* Bg = B16 + (size_t)(n0 + wave * 32) * C;
  unsigned short* Al = As + wave * 32 * 32;
  unsigned short* Bl = Bs + wave * 32 * 32;

  for (int k0 = 0; k0 < C; k0 += 32) {
    async_copy16(Ag + (size_t)srow * C + k0 + kc, Al);
    async_copy16(Ag + (size_t)(16 + srow) * C + k0 + kc, Al + 16 * 32);
    async_copy16(Bg + (size_t)srow * C + k0 + kc, Bl);
    async_copy16(Bg + (size_t)(16 + srow) * C + k0 + kc, Bl + 16 * 32);
    __syncthreads();

    bf16x8 af[4], bfr[4];
#pragma unroll
    for (int i = 0; i < 4; ++i)
      af[i] = *(const bf16x8*)&As[(size_t)(wm + i * 16 + rl) * 32 + kq];
#pragma unroll
    for (int j = 0; j < 4; ++j)
      bfr[j] = *(const bf16x8*)&Bs[(size_t)(wn + j * 16 + rl) * 32 + kq];
#pragma unroll
    for (int i = 0; i < 4; ++i)
#pragma unroll
      for (int j = 0; j < 4; ++j)
        acc[i][j] = __builtin_amdgcn_mfma_f32_16x16x32_bf16(
            af[i], bfr[j], acc[i][j], 0, 0, 0);
    __syncthreads();
  }

  int rq = (lane >> 4) * 4;
#pragma unroll
  for (int j = 0; j < 4; ++j) {
    int cn = n0 + wn + j * 16 + rl;
    float bias = bs[cn];
#pragma unroll
    for (int i = 0; i < 4; ++i) {
#pragma unroll
      for (int r = 0; r < 4; ++r) {
        int gm = m0 + wm + i * 16 + rq + r;
        if (gm < M_MOTIFS) out[(size_t)gm * C + cn] = acc[i][j][r] + bias;
      }
    }
  }
}

extern "C" void kernel_launch(void* const* d_in, const int* in_sizes, int n_in,
                              void* d_out, int out_size, void* d_ws, size_t ws_size,
                              hipStream_t stream) {
  const float* s  = (const float*)d_in[0];
  const float* v  = (const float*)d_in[1];
  const int*   seg = (const int*)d_in[2];
  const float* Ws = (const float*)d_in[3];
  const float* bs = (const float*)d_in[4];
  const float* Wv = (const float*)d_in[5];
  const float* bv = (const float*)d_in[6];

  float* out   = (float*)d_out;
  float* s_out = out;
  float* v_out = out + (size_t)M_MOTIFS * C;

  // ws layout (~26.9 MB of the ~819 MB ws):
  // [cnt M][offs M][nodelist N][blocksums 256][Ws_bf16 64K][s_motif M*C bf16]
  int* cnt       = (int*)d_ws;
  int* offs      = cnt + M_MOTIFS;
  int* nodelist  = offs + M_MOTIFS;
  int* blocksums = nodelist + N_NODES;
  unsigned short* Wsb     = (unsigned short*)(blocksums + 256);
  unsigned short* s_motif = Wsb + (size_t)C * C;

  hipMemsetAsync(cnt, 0, M_MOTIFS * sizeof(int), stream);

  count_kernel<<<(N_NODES + 255) / 256, 256, 0, stream>>>(seg, cnt, N_NODES);
  scan_blocksum_kernel<<<NB, SCAN_B, 0, stream>>>(cnt, blocksums);
  scan_top_kernel<<<1, SCAN_B, 0, stream>>>(blocksums);
  scan_final_kernel<<<NB, SCAN_B, 0, stream>>>(cnt, blocksums, offs);
  place_kernel<<<(N_NODES + 255) / 256, 256, 0, stream>>>(seg, offs, nodelist,
                                                          N_NODES);
  cvt_ws_kernel<<<(C * C + 255) / 256, 256, 0, stream>>>(Ws, Wsb);
  {
    int threads = M_MOTIFS * 64;  // one wave per motif
    gather_kernel<<<(threads + 255) / 256, 256, 0, stream>>>(
        s, v, offs, nodelist, Wv, bv, s_motif, v_out);
  }
  {
    dim3 grid((M_MOTIFS + 127) / 128, C / 128);
    gemm_mfma_kernel<<<grid, 256, 0, stream>>>(s_motif, Wsb, bs, s_out);
  }
}